// Round 2
// baseline (287.071 us; speedup 1.0000x reference)
//
#include <hip/hip_runtime.h>
#include <hip/hip_bf16.h>
#include <math.h>

// Problem constants
#define B_   128
#define C_   256
#define K_   64     // HZ*WZ (corr rows)
#define N_   1024   // HX*WX (corr cols)
#define H_   32
#define W_   32
#define TC_  8
#define L_   64     // 2*H
#define EPS_ 1e-5f

typedef __attribute__((address_space(3))) void       as3_void;
typedef const __attribute__((address_space(1))) void as1_void;

__device__ __forceinline__ void gload16(const float* g, float* lds) {
    __builtin_amdgcn_global_load_lds((as1_void*)g, (as3_void*)lds, 16, 0, 0);
}

// ---------------------------------------------------------------------------
// Kernel A: per-batch corr = z^T x (64 x 1024, K=256), fused pooling.
// grid (2 n-tiles, 128 batches), block 256, 1 block/CU.
// Block tile 64k x 512n; per-thread 8k x 16n (LDS/VALU ratio 0.1875 -> VALU-bound).
// Double-buffered LDS staged with global_load_lds(16B); x staged with
// pre-swizzled global source (sigma(s)=s^((s>>3)&7) on 16B slots, involution)
// so the strided x-fragment ds_read_b128s avoid the 16-way bank conflict.
// n-tile of 512 == 16 full h-rows -> x_h direct; x_w partial (2 blocks) -> atomic.
// ---------------------------------------------------------------------------
__global__ __launch_bounds__(256, 1) void kA_corr(const float* __restrict__ z,
                                                  const float* __restrict__ x,
                                                  float* __restrict__ corr,
                                                  float* __restrict__ xcat)
{
    __shared__ float zs[2][32][64];    // 16 KB  [buf][c][k]
    __shared__ float xs[2][32][512];   // 128 KB [buf][c][n] (16B slots swizzled)

    const int nt   = blockIdx.x;       // 0..1
    const int b    = blockIdx.y;
    const int tid  = threadIdx.x;
    const int wv   = tid >> 6;
    const int lane = tid & 63;
    const int tk   = tid >> 5;         // 0..7  -> k0 = tk*8
    const int tn   = tid & 31;         // 0..31 -> n0 = tn*16

    const float* zb = z + (size_t)b * C_ * K_;
    const float* xb = x + (size_t)b * C_ * N_ + nt * 512;

    // swizzled 16B-slot indices for this thread's 4 x-fragment reads
    int sx[4];
    #pragma unroll
    for (int r = 0; r < 4; ++r) {
        int s = tn * 4 + r;
        sx[r] = s ^ ((s >> 3) & 7);
    }

    float acc[8][16] = {};

    auto stage = [&](int buf, int cs) {
        const int cc = cs * 32;
        #pragma unroll
        for (int q = 0; q < 18; ++q) {
            int ch = wv + 4 * q;               // wave-uniform chunk id 0..71
            if (ch < 8) {                      // z chunk: 4 rows of 64 floats
                int row = ch * 4 + (lane >> 4);
                int col = (lane & 15) * 4;
                gload16(zb + (size_t)(cc + row) * K_ + col, &zs[buf][ch * 4][0]);
            } else {                           // x chunk: 64 float4 slots
                int xc  = ch - 8;              // 0..63
                int qf  = xc * 64 + lane;      // flat 16B-slot index in buffer
                int row = qf >> 7;
                int sp  = qf & 127;            // physical slot in row
                int sl  = sp ^ ((sp >> 3) & 7);// logical slot whose data lands here
                gload16(xb + (size_t)(cc + row) * N_ + sl * 4,
                        &xs[buf][0][0] + xc * 256);
            }
        }
    };

    stage(0, 0);
    asm volatile("s_waitcnt vmcnt(0)" ::: "memory");
    __syncthreads();

    for (int cs = 0; cs < 8; ++cs) {
        const int cur = cs & 1;
        if (cs < 7) stage(cur ^ 1, cs + 1);

        #pragma unroll 4
        for (int c = 0; c < 32; ++c) {
            const float4* zrow = (const float4*)&zs[cur][c][0];
            const float4* xrow = (const float4*)&xs[cur][c][0];
            float4 z0 = zrow[tk * 2];
            float4 z1 = zrow[tk * 2 + 1];
            float4 xf0 = xrow[sx[0]];
            float4 xf1 = xrow[sx[1]];
            float4 xf2 = xrow[sx[2]];
            float4 xf3 = xrow[sx[3]];
            float za[8]  = {z0.x, z0.y, z0.z, z0.w, z1.x, z1.y, z1.z, z1.w};
            float xa[16] = {xf0.x, xf0.y, xf0.z, xf0.w,
                            xf1.x, xf1.y, xf1.z, xf1.w,
                            xf2.x, xf2.y, xf2.z, xf2.w,
                            xf3.x, xf3.y, xf3.z, xf3.w};
            #pragma unroll
            for (int i = 0; i < 8; ++i)
                #pragma unroll
                for (int j = 0; j < 16; ++j)
                    acc[i][j] = fmaf(za[i], xa[j], acc[i][j]);
        }

        asm volatile("s_waitcnt vmcnt(0)" ::: "memory");
        __syncthreads();
    }

    // ---- corr write (into d_out) ----
    float* cb = corr + (size_t)b * K_ * N_ + nt * 512;
    #pragma unroll
    for (int i = 0; i < 8; ++i) {
        #pragma unroll
        for (int r = 0; r < 4; ++r) {
            float4 v = make_float4(acc[i][4*r], acc[i][4*r+1],
                                   acc[i][4*r+2], acc[i][4*r+3]);
            *(float4*)&cb[(size_t)(tk * 8 + i) * N_ + tn * 16 + r * 4] = v;
        }
    }

    // ---- pooling epilogue (overlay LDS; all compute reads done at last barrier) ----
    float (*pwbuf)[64][32] = (float (*)[64][32]) & xs[0][0][0];  // 128 KB
    float (*ph)[32]        = (float (*)[32]) & zs[0][0][0];      // 8 KB

    const int hl  = tn >> 1;   // local h 0..15
    const int par = tn & 1;    // which 16-w half

    #pragma unroll
    for (int i = 0; i < 8; ++i) {
        float rsum = 0.f;
        #pragma unroll
        for (int j = 0; j < 16; ++j) {
            pwbuf[hl][tk * 8 + i][par * 16 + j] = acc[i][j];
            rsum += acc[i][j];
        }
        ph[tk * 8 + i][tn] = rsum;
    }
    __syncthreads();

    float* xcb = xcat + (size_t)b * K_ * L_;
    // x_h: complete for h = nt*16 .. nt*16+15 -> direct store
    #pragma unroll
    for (int q = 0; q < 4; ++q) {
        int idx = tid + q * 256;           // 0..1023
        int k = idx >> 4, hh = idx & 15;
        float s = ph[k][2 * hh] + ph[k][2 * hh + 1];
        xcb[k * L_ + nt * 16 + hh] = s * (1.f / 32.f);
    }
    // x_w: partial over 16 of 32 h -> atomic accumulate (2 blocks/batch)
    #pragma unroll
    for (int q = 0; q < 8; ++q) {
        int idx = tid + q * 256;           // 0..2047
        int k = idx >> 5, w = idx & 31;
        float s = 0.f;
        #pragma unroll
        for (int h2 = 0; h2 < 16; ++h2) s += pwbuf[h2][k][w];
        atomicAdd(&xcb[k * L_ + 32 + w], s * (1.f / 32.f));
    }
}

// ---------------------------------------------------------------------------
// Kernel B: y_pre = conv1_w @ xcat + b1 ; accumulate BN stats (sum, sumsq)
// ---------------------------------------------------------------------------
__global__ __launch_bounds__(256) void kB_conv1(const float* __restrict__ xcat,
                                                const float* __restrict__ w1,
                                                const float* __restrict__ b1,
                                                float* __restrict__ ypre,
                                                float* __restrict__ stats)
{
    __shared__ float xc[64 * 64];
    __shared__ float w1s[TC_ * 64];
    __shared__ float ys[TC_ * 64];

    const int b   = blockIdx.x;
    const int tid = threadIdx.x;
    const float* xcb = xcat + (size_t)b * K_ * L_;

    #pragma unroll
    for (int i = 0; i < 4; ++i) {
        int f4 = tid + i * 256;
        *(float4*)&xc[f4 * 4] = *(const float4*)&xcb[f4 * 4];
    }
    if (tid < 128) *(float4*)&w1s[tid * 4] = *(const float4*)&w1[tid * 4];
    __syncthreads();

    const int o0 = tid >> 6;
    const int l  = tid & 63;
    float y0 = 0.f, y1 = 0.f;
    #pragma unroll 8
    for (int k = 0; k < 64; ++k) {
        float xv = xc[k * 64 + l];
        y0 = fmaf(w1s[o0 * 64 + k],       xv, y0);
        y1 = fmaf(w1s[(o0 + 4) * 64 + k], xv, y1);
    }
    y0 += b1[o0];
    y1 += b1[o0 + 4];
    ypre[((size_t)b * TC_ + o0)     * L_ + l] = y0;
    ypre[((size_t)b * TC_ + o0 + 4) * L_ + l] = y1;
    ys[o0 * L_ + l]       = y0;
    ys[(o0 + 4) * L_ + l] = y1;
    __syncthreads();

    if (tid < TC_) {
        float s = 0.f, sq = 0.f;
        for (int q = 0; q < L_; ++q) {
            float v = ys[tid * L_ + q];
            s += v;
            sq = fmaf(v, v, sq);
        }
        atomicAdd(&stats[tid],       s);
        atomicAdd(&stats[TC_ + tid], sq);
    }
}

// ---------------------------------------------------------------------------
// Kernel D: BN apply + h-swish + conv2/conv3 + sigmoid
// ---------------------------------------------------------------------------
__global__ __launch_bounds__(256) void kD_gate(const float* __restrict__ ypre,
                                               const float* __restrict__ stats,
                                               const float* __restrict__ gamma,
                                               const float* __restrict__ beta,
                                               const float* __restrict__ w2,
                                               const float* __restrict__ b2,
                                               const float* __restrict__ w3,
                                               const float* __restrict__ b3,
                                               float* __restrict__ outh,
                                               float* __restrict__ outw)
{
    __shared__ float yn[TC_ * L_];
    __shared__ float w2s[K_ * TC_];
    __shared__ float w3s[K_ * TC_];
    __shared__ float b2s[K_], b3s[K_];

    const int b   = blockIdx.x;
    const int tid = threadIdx.x;
    const float inv_n = 1.f / (float)(B_ * L_);

    #pragma unroll
    for (int r = 0; r < 2; ++r) {
        int idx = tid + r * 256;
        int o   = idx >> 6;
        float mu  = stats[o] * inv_n;
        float var = stats[TC_ + o] * inv_n - mu * mu;
        float v = ypre[(size_t)b * TC_ * L_ + idx];
        v = (v - mu) * (1.f / sqrtf(var + EPS_)) * gamma[o] + beta[o];
        v = v * fminf(fmaxf(v + 3.f, 0.f), 6.f) * (1.f / 6.f);
        yn[idx] = v;
    }
    if (tid < 128)      *(float4*)&w2s[tid * 4]         = *(const float4*)&w2[tid * 4];
    else                *(float4*)&w3s[(tid - 128) * 4] = *(const float4*)&w3[(tid - 128) * 4];
    if (tid < 64)       b2s[tid]      = b2[tid];
    else if (tid < 128) b3s[tid - 64] = b3[tid - 64];
    __syncthreads();

    #pragma unroll
    for (int r = 0; r < 16; ++r) {
        int idx   = tid + r * 256;
        int which = idx >> 11;
        int o     = (idx >> 5) & 63;
        int p     = idx & 31;
        const float* wsm = which ? w3s : w2s;
        const float* bsm = which ? b3s : b2s;
        float s = bsm[o];
        #pragma unroll
        for (int tt = 0; tt < TC_; ++tt)
            s = fmaf(wsm[o * TC_ + tt], yn[tt * L_ + which * H_ + p], s);
        s = 1.f / (1.f + __expf(-s));
        float* dst = which ? outw : outh;
        dst[((size_t)b * K_ + o) * H_ + p] = s;
    }
}

// ---------------------------------------------------------------------------
// Kernel E: out = corr * out_w[w] * out_h[h], in place on d_out.
// ---------------------------------------------------------------------------
__global__ __launch_bounds__(256) void kE_final(float* __restrict__ out,
                                                const float* __restrict__ outh,
                                                const float* __restrict__ outw)
{
    int idx = blockIdx.x * 256 + threadIdx.x;
    int w4 = idx & 7;
    int h  = (idx >> 3) & 31;
    int bk = idx >> 8;
    float4 c4 = ((const float4*)out)[idx];
    float  oh = outh[bk * H_ + h];
    float4 ow = *(const float4*)&outw[bk * H_ + w4 * 4];
    c4.x *= ow.x * oh;
    c4.y *= ow.y * oh;
    c4.z *= ow.z * oh;
    c4.w *= ow.w * oh;
    ((float4*)out)[idx] = c4;
}

// ---------------------------------------------------------------------------
extern "C" void kernel_launch(void* const* d_in, const int* in_sizes, int n_in,
                              void* d_out, int out_size, void* d_ws, size_t ws_size,
                              hipStream_t stream)
{
    const float* z     = (const float*)d_in[0];
    const float* x     = (const float*)d_in[1];
    const float* w1    = (const float*)d_in[2];
    const float* b1    = (const float*)d_in[3];
    const float* gamma = (const float*)d_in[4];
    const float* beta  = (const float*)d_in[5];
    const float* w2    = (const float*)d_in[6];
    const float* b2    = (const float*)d_in[7];
    const float* w3    = (const float*)d_in[8];
    const float* b3    = (const float*)d_in[9];
    float* out = (float*)d_out;
    float* ws  = (float*)d_ws;

    // workspace layout (floats)
    float* xcat  = ws;                 // B*64*64 = 524288
    float* stats = ws + 524288;        // 16
    float* ypre  = ws + 524304;        // B*8*64  = 65536
    float* outh  = ws + 589840;        // B*64*32 = 262144
    float* outw  = ws + 851984;        // B*64*32 = 262144

    hipMemsetAsync(ws, 0, (size_t)(524288 + 16) * sizeof(float), stream);

    kA_corr <<<dim3(2, B_), 256, 0, stream>>>(z, x, out, xcat);
    kB_conv1<<<B_,          256, 0, stream>>>(xcat, w1, b1, ypre, stats);
    kD_gate <<<B_,          256, 0, stream>>>(ypre, stats, gamma, beta,
                                              w2, b2, w3, b3, outh, outw);
    kE_final<<<(B_ * K_ * N_) / (256 * 4), 256, 0, stream>>>(out, outh, outw);
}